// Round 11
// baseline (300.501 us; speedup 1.0000x reference)
//
#include <hip/hip_runtime.h>
#include <hip/hip_bf16.h>
#include <math.h>

// ---------------------------------------------------------------------------
// EncoderLayer, bf16-MFMA mixed precision for MI355X (gfx950).
// B=8, S=2048, D=512, H=8, DK=64, DFF=2048, M=16384.
// All GEMMs + attention matmuls: mfma_f32_16x16x32_bf16 (fp32 accumulate).
// Softmax (exp2 domain), LayerNorm, residuals, bias: fp32.
// Round-11: attention only -- 4 Q-subtiles per wave (64 rows/wave, 512/block,
// 256 blocks = 1/CU). K/V fragment LDS reads now amortize over 4 subtiles
// (DS-cyc/Q-row 10.4 -> 6.4, the measured r8 lever applied again). K/V LDS
// double-buffered -> ONE barrier per KV tile (writes-before-barrier safe:
// a wave 2 iters ahead writes a buffer whose readers passed barrier t+1).
// LDS 112KB/WG (gfx950 allows up to 160KB). GEMM/LN/pack unchanged from r10.
// ---------------------------------------------------------------------------

#define D_MODEL 512
#define NHEAD   8
#define DKH     64
#define SEQ     2048
#define BATCH   8
#define DFF     2048
#define MROWS   (BATCH * SEQ)          // 16384
#define QKVLD   1536                   // fused q|k|v row stride

typedef __bf16 bf16x8 __attribute__((ext_vector_type(8)));
typedef float  f32x4  __attribute__((ext_vector_type(4)));

__device__ __forceinline__ unsigned short f2bf(float f) {
    union { float f; unsigned u; } v; v.f = f;
    return (unsigned short)((v.u + 0x7FFFu + ((v.u >> 16) & 1u)) >> 16);
}

__device__ __forceinline__ float bf2f(unsigned short u) {
    union { unsigned u; float f; } v; v.u = (unsigned)u << 16;
    return v.f;
}

__device__ __forceinline__ unsigned cvtpk(float a, float b) {   // bf16(a)|bf16(b)<<16, RNE
    unsigned r;
    asm("v_cvt_pk_bf16_f32 %0, %1, %2" : "=v"(r) : "v"(a), "v"(b));
    return r;
}

__device__ __forceinline__ float fexp2(float x) {   // raw v_exp_f32 (2^x)
    float r; asm("v_exp_f32 %0, %1" : "=v"(r) : "v"(x)); return r;
}

__device__ __forceinline__ f32x4 mfma16(bf16x8 a, bf16x8 b, f32x4 c) {
    return __builtin_amdgcn_mfma_f32_16x16x32_bf16(a, b, c, 0, 0, 0);
}

// async global -> LDS, 16 B per lane; lds base must be wave-uniform
__device__ __forceinline__ void gld_lds16(const unsigned short* g, unsigned short* l) {
    __builtin_amdgcn_global_load_lds(
        (const __attribute__((address_space(1))) unsigned int*)g,
        (__attribute__((address_space(3))) unsigned int*)l, 16, 0, 0);
}

// ---------------------------------------------------------------------------
// bf16 MFMA GEMM: C[M,N] = A[M,K] * Bt[N,K]^T  (+bias, +relu, +residual)
// 128x128 tile, BK=32, 256 threads = 4 waves, each wave a 64x64 quadrant
// (4x4 fragments of 16x16x32). Double-buffered global_load_lds staging
// (issue next tile before MFMAs of current; one barrier per K-step).
// RESMODE: 0 none, 1 fp32, 2 bf16.   (unchanged from round 10)
// ---------------------------------------------------------------------------
template<bool BIAS, bool RELU, int RESMODE, bool OUTF32>
__global__ __launch_bounds__(256)
void mfma_gemm(const unsigned short* __restrict__ Av,
               const unsigned short* __restrict__ Bt,
               const float* __restrict__ bias, const void* __restrict__ resv,
               void* __restrict__ Cv, int Kdim, int lda, int ldc)
{
    __shared__ unsigned short As[2][128][32];
    __shared__ unsigned short Bs[2][128][32];

    const int tid  = threadIdx.x;
    const int lane = tid & 63;
    const int w    = tid >> 6;
    const int mq   = (w >> 1) << 6;    // wave quadrant row
    const int nq   = (w & 1) << 6;     // wave quadrant col
    const int lrow = lane & 15;
    const int g    = lane >> 4;
    const int lk   = g << 3;           // k offset of this lane's 8 elems

    const int row0 = blockIdx.y << 7;
    const int col0 = blockIdx.x << 7;

    const int c0   = w << 5;
    const int srow = lane >> 2;
    const int scol = (lane & 3) << 3;
    const size_t aoff = (size_t)(row0 + c0 + srow) * lda  + scol;
    const size_t boff = (size_t)(col0 + c0 + srow) * Kdim + scol;

    auto stage = [&](int buf, int kt) {
        gld_lds16(Av + aoff + kt,                        &As[buf][c0     ][0]);
        gld_lds16(Av + aoff + (size_t)16 * lda  + kt,    &As[buf][c0 + 16][0]);
        gld_lds16(Bt + boff + kt,                        &Bs[buf][c0     ][0]);
        gld_lds16(Bt + boff + (size_t)16 * Kdim + kt,    &Bs[buf][c0 + 16][0]);
    };

    const f32x4 zero = {0.f, 0.f, 0.f, 0.f};
    f32x4 acc[4][4];
    #pragma unroll
    for (int i = 0; i < 4; ++i)
        #pragma unroll
        for (int j = 0; j < 4; ++j) acc[i][j] = zero;

    stage(0, 0);
    __syncthreads();           // drains vmcnt -> buf0 visible

    int cur = 0;
    for (int kt = 0; kt < Kdim; kt += 32) {
        if (kt + 32 < Kdim) stage(cur ^ 1, kt + 32);   // in flight over compute

        bf16x8 af[4], bfv[4];
        #pragma unroll
        for (int mf = 0; mf < 4; ++mf)
            af[mf] = *(const bf16x8*)&As[cur][mq + mf * 16 + lrow][lk];
        #pragma unroll
        for (int nf = 0; nf < 4; ++nf)
            bfv[nf] = *(const bf16x8*)&Bs[cur][nq + nf * 16 + lrow][lk];
        #pragma unroll
        for (int mf = 0; mf < 4; ++mf)
            #pragma unroll
            for (int nf = 0; nf < 4; ++nf)
                acc[mf][nf] = mfma16(af[mf], bfv[nf], acc[mf][nf]);

        __syncthreads();       // drains vmcnt (next buf ready) + read fence
        cur ^= 1;
    }

    // epilogue: C/D layout col = lane&15, row = 4*(lane>>4)+reg
    const int orow = row0 + mq + g * 4;
    const int ocol = col0 + nq + lrow;
    #pragma unroll
    for (int mf = 0; mf < 4; ++mf) {
        #pragma unroll
        for (int nf = 0; nf < 4; ++nf) {
            const int cc = ocol + nf * 16;
            float bv = 0.f;
            if constexpr (BIAS) bv = bias[cc];
            float v[4];
            #pragma unroll
            for (int r = 0; r < 4; ++r) {
                const int rr = orow + mf * 16 + r;
                v[r] = acc[mf][nf][r];
                if constexpr (BIAS) v[r] += bv;
                if constexpr (RELU) v[r] = fmaxf(v[r], 0.f);
                if constexpr (RESMODE == 1)
                    v[r] += ((const float*)resv)[(size_t)rr * ldc + cc];
                if constexpr (RESMODE == 2)
                    v[r] += bf2f(((const unsigned short*)resv)[(size_t)rr * ldc + cc]);
                if constexpr (OUTF32) ((float*)Cv)[(size_t)rr * ldc + cc] = v[r];
            }
            if constexpr (!OUTF32) {
                const unsigned u01 = cvtpk(v[0], v[1]);
                const unsigned u23 = cvtpk(v[2], v[3]);
                unsigned short* cp = (unsigned short*)Cv + (size_t)(orow + mf * 16) * ldc + cc;
                cp[0]                 = (unsigned short)u01;
                cp[(size_t)ldc]       = (unsigned short)(u01 >> 16);
                cp[(size_t)ldc * 2]   = (unsigned short)u23;
                cp[(size_t)ldc * 3]   = (unsigned short)(u23 >> 16);
            }
        }
    }
}

// ---------------------------------------------------------------------------
// Flash attention v4: 8 waves x 64 Q-rows (4 x 16-row subtiles) = 512 Q-rows
// per block, 256 blocks (1/CU), KV tiles of 64 double-buffered in LDS ->
// ONE barrier per tile. K/V fragment reads amortized over 4 subtiles.
// Softmax exp2-domain, defer-max, lazy sum. P in permuted-kv layout
// (c = 4*lrow + nf, ds_write_b64); V' transposed into the same columns.
// XCD swizzle: 4 q-tile blocks x 8 bh per XCD.
// ---------------------------------------------------------------------------
__device__ __forceinline__ void softmax_store(
    f32x4* sacc, float* mrun, float* lpart, f32x4* oacc,
    unsigned short (*Ps)[76], int rowbase, int g, int lrow)
{
    float pmax[4];
    bool need = false;
    #pragma unroll
    for (int r = 0; r < 4; ++r) {
        pmax[r] = fmaxf(fmaxf(sacc[0][r], sacc[1][r]),
                        fmaxf(sacc[2][r], sacc[3][r]));
        need |= (pmax[r] > mrun[r] + 8.f);
    }
    if (__any(need)) {   // rare after first tile: full max-reduce + rescale
        #pragma unroll
        for (int r = 0; r < 4; ++r) {
            float mt = pmax[r];
            mt = fmaxf(mt, __shfl_xor(mt, 1, 16));
            mt = fmaxf(mt, __shfl_xor(mt, 2, 16));
            mt = fmaxf(mt, __shfl_xor(mt, 4, 16));
            mt = fmaxf(mt, __shfl_xor(mt, 8, 16));
            const float mnew = fmaxf(mrun[r], mt);
            const float alpha = fexp2(mrun[r] - mnew);  // first tile: 0
            mrun[r] = mnew;
            lpart[r] *= alpha;
            #pragma unroll
            for (int nf = 0; nf < 4; ++nf) oacc[nf][r] *= alpha;
        }
    }
    #pragma unroll
    for (int r = 0; r < 4; ++r) {
        const float p0 = fexp2(sacc[0][r] - mrun[r]);
        const float p1 = fexp2(sacc[1][r] - mrun[r]);
        const float p2 = fexp2(sacc[2][r] - mrun[r]);
        const float p3 = fexp2(sacc[3][r] - mrun[r]);
        lpart[r] += (p0 + p1) + (p2 + p3);
        uint2 u;
        u.x = cvtpk(p0, p1);     // cols 4*lrow, 4*lrow+1  (nf=0,1)
        u.y = cvtpk(p2, p3);     // cols 4*lrow+2, +3      (nf=2,3)
        *(uint2*)&Ps[rowbase + g * 4 + r][4 * lrow] = u;
    }
}

__global__ __launch_bounds__(512, 2)
void mfma_attn(unsigned short* __restrict__ qkv)
{
    __shared__ unsigned short Ks[2][64][72];   // K tile [buf][kv][dk]
    __shared__ unsigned short Vt[2][64][72];   // V' transposed [buf][dk][c(kv)]
    __shared__ unsigned short Ps[512][76];     // P' [qrow][c(kv)]

    const int tid  = threadIdx.x;
    const int lane = tid & 63;
    const int w    = tid >> 6;
    const int lrow = lane & 15;
    const int g    = lane >> 4;
    const int lk   = g << 3;

    // XCD swizzle: 256 blocks = 8 xcd x (8 bh-groups x 4 q-tiles)
    const int bid  = blockIdx.x;
    const int idx  = bid >> 3;
    const int bh   = (bid & 7) * 8 + (idx & 7);
    const int b  = bh >> 3, h = bh & 7;
    const int s0 = (idx >> 3) << 9;              // q-tile start (512 rows)

    unsigned short* qptr = qkv + ((size_t)(b * SEQ + s0)) * QKVLD + h * DKH;
    const unsigned short* kbase = qkv + ((size_t)(b * SEQ)) * QKVLD + 512 + h * DKH;
    const unsigned short* vbase = qkv + ((size_t)(b * SEQ)) * QKVLD + 1024 + h * DKH;

    // Q fragments for 4 16-row sub-tiles (pre-scaled 0.125*log2e via pack)
    bf16x8 qf[4][2];
    #pragma unroll
    for (int sub = 0; sub < 4; ++sub) {
        const unsigned short* qp = qptr + (size_t)(w * 64 + sub * 16 + lrow) * QKVLD;
        qf[sub][0] = *(const bf16x8*)(qp + lk);
        qf[sub][1] = *(const bf16x8*)(qp + 32 + lk);
    }

    // staging indices
    const int kr = tid >> 3, kc = (tid & 7) << 3;   // K: 64 rows x 64 cols
    const int vr = tid & 63, vc = (tid >> 6) << 3;  // V: row=vr, 8-col slab
    const int cvr = ((vr & 15) << 2) | (vr >> 4);   // permuted col of kv=vr

    uint4 kreg, vreg;
    auto loadKV = [&](int t0) {
        kreg = *(const uint4*)(kbase + (size_t)(t0 + kr) * QKVLD + kc);
        vreg = *(const uint4*)(vbase + (size_t)(t0 + vr) * QKVLD + vc);
    };
    loadKV(0);

    const f32x4 zero = {0.f, 0.f, 0.f, 0.f};
    f32x4 oacc[4][4];                 // [sub][dk frag]
    float m[4][4], l[4][4];           // [sub][r]
    #pragma unroll
    for (int s = 0; s < 4; ++s)
        #pragma unroll
        for (int i = 0; i < 4; ++i) {
            oacc[s][i] = zero; m[s][i] = -INFINITY; l[s][i] = 0.f;
        }

    for (int t0 = 0; t0 < SEQ; t0 += 64) {
        const int cur = (t0 >> 6) & 1;
        // write staged K/V regs into buf[cur]; single barrier per tile.
        // Safe: a wave writing buf[cur] at iter t+2 has passed barrier t+1,
        // which every wave only reaches after finishing its buf[cur] reads
        // from iter t.
        *(uint4*)&Ks[cur][kr][kc] = kreg;
        {
            const unsigned short* vu = (const unsigned short*)&vreg;
            #pragma unroll
            for (int j = 0; j < 8; ++j) Vt[cur][vc + j][cvr] = vu[j];
        }
        __syncthreads();

        if (t0 + 64 < SEQ) loadKV(t0 + 64);   // prefetch, in flight over compute

        // K fragments: read ONCE, feed all 4 subtiles' QK MFMAs
        bf16x8 kf[2][4];
        #pragma unroll
        for (int kk = 0; kk < 2; ++kk)
            #pragma unroll
            for (int nf = 0; nf < 4; ++nf)
                kf[kk][nf] = *(const bf16x8*)&Ks[cur][nf * 16 + lrow][kk * 32 + lk];

        // per-subtile: QK -> softmax -> P store
        #pragma unroll
        for (int sub = 0; sub < 4; ++sub) {
            f32x4 sacc[4];
            #pragma unroll
            for (int nf = 0; nf < 4; ++nf) sacc[nf] = zero;
            __builtin_amdgcn_s_setprio(1);
            #pragma unroll
            for (int kk = 0; kk < 2; ++kk)
                #pragma unroll
                for (int nf = 0; nf < 4; ++nf)
                    sacc[nf] = mfma16(qf[sub][kk], kf[kk][nf], sacc[nf]);
            __builtin_amdgcn_s_setprio(0);
            softmax_store(sacc, m[sub], l[sub], oacc[sub], Ps,
                          w * 64 + sub * 16, g, lrow);
        }

        // O += P' V'   (vf read once per kk, shared across 4 subtiles)
        __builtin_amdgcn_s_setprio(1);
        #pragma unroll
        for (int kk = 0; kk < 2; ++kk) {
            bf16x8 vf[4];
            #pragma unroll
            for (int nf = 0; nf < 4; ++nf)
                vf[nf] = *(const bf16x8*)&Vt[cur][nf * 16 + lrow][kk * 32 + lk];
            #pragma unroll
            for (int sub = 0; sub < 4; ++sub) {
                const bf16x8 pf =
                    *(const bf16x8*)&Ps[w * 64 + sub * 16 + lrow][kk * 32 + lk];
                #pragma unroll
                for (int nf = 0; nf < 4; ++nf)
                    oacc[sub][nf] = mfma16(pf, vf[nf], oacc[sub][nf]);
            }
        }
        __builtin_amdgcn_s_setprio(0);
    }

    // final row-sum reductions, normalize, write O bf16 in place
    #pragma unroll
    for (int sub = 0; sub < 4; ++sub) {
        #pragma unroll
        for (int r = 0; r < 4; ++r) {
            float lv = l[sub][r];
            lv += __shfl_xor(lv, 1, 16);
            lv += __shfl_xor(lv, 2, 16);
            lv += __shfl_xor(lv, 4, 16);
            lv += __shfl_xor(lv, 8, 16);
            const float inv = 1.f / lv;
            #pragma unroll
            for (int nf = 0; nf < 4; ++nf)
                qptr[(size_t)(w * 64 + sub * 16 + g * 4 + r) * QKVLD
                     + nf * 16 + lrow] = f2bf(oacc[sub][nf][r] * inv);
        }
    }
}

// ---------------------------------------------------------------------------
// LayerNorm rows of 512; one wave per row. WF32: fp32 out; WB16: bf16 out.
// ---------------------------------------------------------------------------
template<bool WF32, bool WB16>
__global__ __launch_bounds__(256)
void ln_kernel(const float* __restrict__ in, const float* __restrict__ gg,
               const float* __restrict__ bb, float* __restrict__ outf,
               unsigned short* __restrict__ outb)
{
    const int row = blockIdx.x * 4 + (threadIdx.x >> 6);
    const int lane = threadIdx.x & 63;
    const float* p = in + (size_t)row * D_MODEL;

    const float4 a = *(const float4*)(p + lane * 4);
    const float4 c = *(const float4*)(p + 256 + lane * 4);
    float sum = a.x + a.y + a.z + a.w + c.x + c.y + c.z + c.w;
    float sq  = a.x*a.x + a.y*a.y + a.z*a.z + a.w*a.w
              + c.x*c.x + c.y*c.y + c.z*c.z + c.w*c.w;
    #pragma unroll
    for (int msk = 1; msk < 64; msk <<= 1) {
        sum += __shfl_xor(sum, msk, 64);
        sq  += __shfl_xor(sq,  msk, 64);
    }
    const float mean = sum * (1.f / 512.f);
    const float var  = sq * (1.f / 512.f) - mean * mean;
    const float rs   = rsqrtf(var + 1e-5f);

    const float4 g0 = *(const float4*)(gg + lane * 4);
    const float4 g1 = *(const float4*)(gg + 256 + lane * 4);
    const float4 b0 = *(const float4*)(bb + lane * 4);
    const float4 b1 = *(const float4*)(bb + 256 + lane * 4);

    float4 o0, o1;
    o0.x = (a.x - mean) * rs * g0.x + b0.x;
    o0.y = (a.y - mean) * rs * g0.y + b0.y;
    o0.z = (a.z - mean) * rs * g0.z + b0.z;
    o0.w = (a.w - mean) * rs * g0.w + b0.w;
    o1.x = (c.x - mean) * rs * g1.x + b1.x;
    o1.y = (c.y - mean) * rs * g1.y + b1.y;
    o1.z = (c.z - mean) * rs * g1.z + b1.z;
    o1.w = (c.w - mean) * rs * g1.w + b1.w;
    if constexpr (WF32) {
        *(float4*)(outf + (size_t)row * D_MODEL + lane * 4) = o0;
        *(float4*)(outf + (size_t)row * D_MODEL + 256 + lane * 4) = o1;
    }
    if constexpr (WB16) {
        uint2 pa, pb;
        pa.x = cvtpk(o0.x, o0.y);
        pa.y = cvtpk(o0.z, o0.w);
        pb.x = cvtpk(o1.x, o1.y);
        pb.y = cvtpk(o1.z, o1.w);
        *(uint2*)(outb + (size_t)row * D_MODEL + lane * 4) = pa;
        *(uint2*)(outb + (size_t)row * D_MODEL + 256 + lane * 4) = pb;
    }
}

// ---------------------------------------------------------------------------
// fp32 -> bf16 cast, 8 elems/thread
// ---------------------------------------------------------------------------
__global__ __launch_bounds__(256)
void cast_bf16(const float* __restrict__ in, unsigned short* __restrict__ out)
{
    const size_t i = ((size_t)blockIdx.x * 256 + threadIdx.x) * 8;
    const float4 a = *(const float4*)(in + i);
    const float4 b = *(const float4*)(in + i + 4);
    uint4 o;
    o.x = cvtpk(a.x, a.y);
    o.y = cvtpk(a.z, a.w);
    o.z = cvtpk(b.x, b.y);
    o.w = cvtpk(b.z, b.w);
    *(uint4*)(out + i) = o;
}

// ---------------------------------------------------------------------------
// Weight packing: per-head q/k/v weights -> rows 0..511 / 512..1023 /
// 1024..1535 of Wqkv[1536][512] bf16. q scaled by 0.125*log2e (exp2 softmax).
// ---------------------------------------------------------------------------
__global__ __launch_bounds__(256)
void pack_qkv(const float* __restrict__ wq, const float* __restrict__ wk,
              const float* __restrict__ wv, unsigned short* __restrict__ Wqkv)
{
    const int idx = blockIdx.x * 256 + threadIdx.x;   // n*512 + d, n in 0..511
    const int n = idx >> 9, d = idx & 511;
    const int h = n >> 6, c = n & 63;
    const size_t src = ((size_t)h * 512 + d) * 64 + c;
    Wqkv[idx]                 = f2bf(wq[src] * 0.18033688f);  // 0.125 * log2(e)
    Wqkv[idx + 512 * 512]     = f2bf(wk[src]);
    Wqkv[idx + 2 * 512 * 512] = f2bf(wv[src]);
}

// LDS-tiled transpose-cast: in fp32 [K][N] -> out bf16 [N][K], 32x32 tiles,
// coalesced reads and writes.
__global__ __launch_bounds__(256)
void pack_t(const float* __restrict__ in, unsigned short* __restrict__ out,
            int K, int N)
{
    __shared__ float t[32][33];
    const int kb = blockIdx.x << 5, nb = blockIdx.y << 5;
    const int c = threadIdx.x & 31, r0 = threadIdx.x >> 5;   // 8 row-groups
    #pragma unroll
    for (int j = 0; j < 32; j += 8)
        t[r0 + j][c] = in[(size_t)(kb + r0 + j) * N + nb + c];
    __syncthreads();
    #pragma unroll
    for (int j = 0; j < 32; j += 8)
        out[(size_t)(nb + r0 + j) * K + kb + c] = f2bf(t[c][r0 + j]);
}

// ---------------------------------------------------------------------------
extern "C" void kernel_launch(void* const* d_in, const int* in_sizes, int n_in,
                              void* d_out, int out_size, void* d_ws, size_t ws_size,
                              hipStream_t stream)
{
    (void)in_sizes; (void)n_in; (void)out_size;

    const float* x    = (const float*)d_in[0];
    const float* wq   = (const float*)d_in[1];
    const float* wk   = (const float*)d_in[2];
    const float* wv   = (const float*)d_in[3];
    const float* wo   = (const float*)d_in[4];
    const float* w1   = (const float*)d_in[5];
    const float* b1   = (const float*)d_in[6];
    const float* w2   = (const float*)d_in[7];
    const float* b2   = (const float*)d_in[8];
    const float* ln1g = (const float*)d_in[9];
    const float* ln1b = (const float*)d_in[10];
    const float* ln2g = (const float*)d_in[11];
    const float* ln2b = (const float*)d_in[12];
    float* out = (float*)d_out;

    // ---- workspace layout (bytes), fixed part ~90.2 MB ----
    const size_t QKV_BYTES = (size_t)MROWS * QKVLD * 2;      // 50.33 MB
    const size_t Y_BYTES   = (size_t)MROWS * D_MODEL * 4;    // 33.55 MB
    unsigned char* base = (unsigned char*)d_ws;
    unsigned short* qkv  = (unsigned short*)(base);
    float*          y    = (float*)(base + QKV_BYTES);
    unsigned short* Wqkv = (unsigned short*)(base + QKV_BYTES + Y_BYTES);
    unsigned short* wo_t = Wqkv + 3 * 512 * 512;
    unsigned short* w1_t = wo_t + 512 * 512;
    unsigned short* w2_t = w1_t + 2048 * 512;
    unsigned short* hid  = w2_t + 2048 * 512;

    const size_t hid_off = (size_t)((unsigned char*)hid - base);
    const size_t avail = (ws_size > hid_off) ? (ws_size - hid_off) : 0;
    int chunk = (int)(avail / ((size_t)DFF * 2));
    chunk &= ~127;
    if (chunk > MROWS) chunk = MROWS;
    if (chunk < 128)   chunk = 128;

    float* y2 = (float*)qkv;                       // qkv dead after WO GEMM
    // d_out doubles as scratch: xb (bf16 x) until LN1, then x1b (bf16 x1).
    unsigned short* xb  = (unsigned short*)d_out;
    unsigned short* x1b = (unsigned short*)d_out;

    // ---- weight packing + x cast ----
    pack_qkv<<<1024, 256, 0, stream>>>(wq, wk, wv, Wqkv);
    pack_t<<<dim3(16, 16), 256, 0, stream>>>(wo, wo_t, 512, 512);
    pack_t<<<dim3(16, 64), 256, 0, stream>>>(w1, w1_t, 512, 2048);
    pack_t<<<dim3(64, 16), 256, 0, stream>>>(w2, w2_t, 2048, 512);
    cast_bf16<<<(MROWS * D_MODEL) / (256 * 8), 256, 0, stream>>>(x, xb);

    const dim3 blk(256);

    // 1) fused q|k|v projection: xb[M][512] @ Wqkv^T -> qkv[M][1536]
    mfma_gemm<false, false, 0, false>
        <<<dim3(12, MROWS / 128), blk, 0, stream>>>(xb, Wqkv, nullptr, nullptr,
                                                    qkv, 512, 512, QKVLD);

    // 2) flash attention (O bf16 in place over q section), XCD-swizzled grid
    mfma_attn<<<dim3(256), dim3(512), 0, stream>>>(qkv);

    // 3) y = O @ wo + x   (fp32 out, fp32 residual)
    mfma_gemm<false, false, 1, true>
        <<<dim3(4, MROWS / 128), blk, 0, stream>>>(qkv, wo_t, nullptr, x, y,
                                                   512, QKVLD, 512);

    // 4) x1 = LN1(y): bf16 only into d_out (FFN2 residual reads bf16)
    ln_kernel<false, true><<<MROWS / 4, blk, 0, stream>>>(y, ln1g, ln1b,
                                                          nullptr, x1b);

    // 5+6) FFN, chunked over rows (chunk multiple of 128)
    for (int r0 = 0; r0 < MROWS; r0 += chunk) {
        const int rows = (r0 + chunk <= MROWS) ? chunk : (MROWS - r0);
        mfma_gemm<true, true, 0, false>
            <<<dim3(DFF / 128, rows / 128), blk, 0, stream>>>(
                x1b + (size_t)r0 * D_MODEL, w1_t, b1, nullptr, hid,
                512, 512, DFF);
        mfma_gemm<true, false, 2, true>
            <<<dim3(4, rows / 128), blk, 0, stream>>>(
                hid, w2_t, b2, x1b + (size_t)r0 * D_MODEL,
                y2 + (size_t)r0 * D_MODEL, DFF, DFF, 512);
    }

    // 7) out = LN2(y2)
    ln_kernel<true, false><<<MROWS / 4, blk, 0, stream>>>(y2, ln2g, ln2b,
                                                          out, nullptr);
}

// Round 12
// 294.844 us; speedup vs baseline: 1.0192x; 1.0192x over previous
//
#include <hip/hip_runtime.h>
#include <hip/hip_bf16.h>
#include <math.h>

// ---------------------------------------------------------------------------
// EncoderLayer, bf16-MFMA mixed precision for MI355X (gfx950).
// B=8, S=2048, D=512, H=8, DK=64, DFF=2048, M=16384.
// All GEMMs + attention matmuls: mfma_f32_16x16x32_bf16 (fp32 accumulate).
// Softmax (exp2 domain), LayerNorm, residuals, bias: fp32.
// Round-12: r10 attention shape (2 subtiles/wave, 256 Q-rows/block, 512
// blocks, 2 blocks/CU) + r11's proven single-barrier double-buffered K/V
// staging (one barrier per KV tile instead of two; LDS 57->74 KB keeps
// 2 blocks/CU). r11's 4-subtile/112KB variant regressed on occupancy
// (1 block/CU, 2 waves/SIMD) and is abandoned. GEMM/LN/pack = r10.
// ---------------------------------------------------------------------------

#define D_MODEL 512
#define NHEAD   8
#define DKH     64
#define SEQ     2048
#define BATCH   8
#define DFF     2048
#define MROWS   (BATCH * SEQ)          // 16384
#define QKVLD   1536                   // fused q|k|v row stride

typedef __bf16 bf16x8 __attribute__((ext_vector_type(8)));
typedef float  f32x4  __attribute__((ext_vector_type(4)));

__device__ __forceinline__ unsigned short f2bf(float f) {
    union { float f; unsigned u; } v; v.f = f;
    return (unsigned short)((v.u + 0x7FFFu + ((v.u >> 16) & 1u)) >> 16);
}

__device__ __forceinline__ float bf2f(unsigned short u) {
    union { unsigned u; float f; } v; v.u = (unsigned)u << 16;
    return v.f;
}

__device__ __forceinline__ unsigned cvtpk(float a, float b) {   // bf16(a)|bf16(b)<<16, RNE
    unsigned r;
    asm("v_cvt_pk_bf16_f32 %0, %1, %2" : "=v"(r) : "v"(a), "v"(b));
    return r;
}

__device__ __forceinline__ float fexp2(float x) {   // raw v_exp_f32 (2^x)
    float r; asm("v_exp_f32 %0, %1" : "=v"(r) : "v"(x)); return r;
}

__device__ __forceinline__ f32x4 mfma16(bf16x8 a, bf16x8 b, f32x4 c) {
    return __builtin_amdgcn_mfma_f32_16x16x32_bf16(a, b, c, 0, 0, 0);
}

// async global -> LDS, 16 B per lane; lds base must be wave-uniform
__device__ __forceinline__ void gld_lds16(const unsigned short* g, unsigned short* l) {
    __builtin_amdgcn_global_load_lds(
        (const __attribute__((address_space(1))) unsigned int*)g,
        (__attribute__((address_space(3))) unsigned int*)l, 16, 0, 0);
}

// ---------------------------------------------------------------------------
// bf16 MFMA GEMM: C[M,N] = A[M,K] * Bt[N,K]^T  (+bias, +relu, +residual)
// 128x128 tile, BK=32, 256 threads = 4 waves, each wave a 64x64 quadrant
// (4x4 fragments of 16x16x32). Double-buffered global_load_lds staging
// (issue next tile before MFMAs of current; one barrier per K-step).
// RESMODE: 0 none, 1 fp32, 2 bf16.   (unchanged from round 10)
// ---------------------------------------------------------------------------
template<bool BIAS, bool RELU, int RESMODE, bool OUTF32>
__global__ __launch_bounds__(256)
void mfma_gemm(const unsigned short* __restrict__ Av,
               const unsigned short* __restrict__ Bt,
               const float* __restrict__ bias, const void* __restrict__ resv,
               void* __restrict__ Cv, int Kdim, int lda, int ldc)
{
    __shared__ unsigned short As[2][128][32];
    __shared__ unsigned short Bs[2][128][32];

    const int tid  = threadIdx.x;
    const int lane = tid & 63;
    const int w    = tid >> 6;
    const int mq   = (w >> 1) << 6;    // wave quadrant row
    const int nq   = (w & 1) << 6;     // wave quadrant col
    const int lrow = lane & 15;
    const int g    = lane >> 4;
    const int lk   = g << 3;           // k offset of this lane's 8 elems

    const int row0 = blockIdx.y << 7;
    const int col0 = blockIdx.x << 7;

    const int c0   = w << 5;
    const int srow = lane >> 2;
    const int scol = (lane & 3) << 3;
    const size_t aoff = (size_t)(row0 + c0 + srow) * lda  + scol;
    const size_t boff = (size_t)(col0 + c0 + srow) * Kdim + scol;

    auto stage = [&](int buf, int kt) {
        gld_lds16(Av + aoff + kt,                        &As[buf][c0     ][0]);
        gld_lds16(Av + aoff + (size_t)16 * lda  + kt,    &As[buf][c0 + 16][0]);
        gld_lds16(Bt + boff + kt,                        &Bs[buf][c0     ][0]);
        gld_lds16(Bt + boff + (size_t)16 * Kdim + kt,    &Bs[buf][c0 + 16][0]);
    };

    const f32x4 zero = {0.f, 0.f, 0.f, 0.f};
    f32x4 acc[4][4];
    #pragma unroll
    for (int i = 0; i < 4; ++i)
        #pragma unroll
        for (int j = 0; j < 4; ++j) acc[i][j] = zero;

    stage(0, 0);
    __syncthreads();           // drains vmcnt -> buf0 visible

    int cur = 0;
    for (int kt = 0; kt < Kdim; kt += 32) {
        if (kt + 32 < Kdim) stage(cur ^ 1, kt + 32);   // in flight over compute

        bf16x8 af[4], bfv[4];
        #pragma unroll
        for (int mf = 0; mf < 4; ++mf)
            af[mf] = *(const bf16x8*)&As[cur][mq + mf * 16 + lrow][lk];
        #pragma unroll
        for (int nf = 0; nf < 4; ++nf)
            bfv[nf] = *(const bf16x8*)&Bs[cur][nq + nf * 16 + lrow][lk];
        #pragma unroll
        for (int mf = 0; mf < 4; ++mf)
            #pragma unroll
            for (int nf = 0; nf < 4; ++nf)
                acc[mf][nf] = mfma16(af[mf], bfv[nf], acc[mf][nf]);

        __syncthreads();       // drains vmcnt (next buf ready) + read fence
        cur ^= 1;
    }

    // epilogue: C/D layout col = lane&15, row = 4*(lane>>4)+reg
    const int orow = row0 + mq + g * 4;
    const int ocol = col0 + nq + lrow;
    #pragma unroll
    for (int mf = 0; mf < 4; ++mf) {
        #pragma unroll
        for (int nf = 0; nf < 4; ++nf) {
            const int cc = ocol + nf * 16;
            float bv = 0.f;
            if constexpr (BIAS) bv = bias[cc];
            float v[4];
            #pragma unroll
            for (int r = 0; r < 4; ++r) {
                const int rr = orow + mf * 16 + r;
                v[r] = acc[mf][nf][r];
                if constexpr (BIAS) v[r] += bv;
                if constexpr (RELU) v[r] = fmaxf(v[r], 0.f);
                if constexpr (RESMODE == 1)
                    v[r] += ((const float*)resv)[(size_t)rr * ldc + cc];
                if constexpr (RESMODE == 2)
                    v[r] += bf2f(((const unsigned short*)resv)[(size_t)rr * ldc + cc]);
                if constexpr (OUTF32) ((float*)Cv)[(size_t)rr * ldc + cc] = v[r];
            }
            if constexpr (!OUTF32) {
                const unsigned u01 = cvtpk(v[0], v[1]);
                const unsigned u23 = cvtpk(v[2], v[3]);
                unsigned short* cp = (unsigned short*)Cv + (size_t)(orow + mf * 16) * ldc + cc;
                cp[0]                 = (unsigned short)u01;
                cp[(size_t)ldc]       = (unsigned short)(u01 >> 16);
                cp[(size_t)ldc * 2]   = (unsigned short)u23;
                cp[(size_t)ldc * 3]   = (unsigned short)(u23 >> 16);
            }
        }
    }
}

// ---------------------------------------------------------------------------
// Flash attention v5: 8 waves x 32 Q-rows (2 x 16-row subtiles) = 256 Q-rows
// per block, 512 blocks (2/CU), KV tiles of 64 DOUBLE-BUFFERED in LDS ->
// ONE barrier per tile (r11-proven pattern: a wave writing buf[cur] at
// iter t+2 passed barrier t+1, which readers of iter t reached only after
// finishing their buf[cur] reads). Softmax exp2-domain, defer-max, lazy
// sum. P in permuted-kv layout (c = 4*lrow + nf, ds_write_b64); V'
// transposed into the same columns. XCD swizzle: 8 bh-groups per XCD.
// ---------------------------------------------------------------------------
__device__ __forceinline__ void softmax_store(
    f32x4* sacc, float* mrun, float* lpart, f32x4* oacc,
    unsigned short (*Ps)[76], int rowbase, int g, int lrow)
{
    float pmax[4];
    bool need = false;
    #pragma unroll
    for (int r = 0; r < 4; ++r) {
        pmax[r] = fmaxf(fmaxf(sacc[0][r], sacc[1][r]),
                        fmaxf(sacc[2][r], sacc[3][r]));
        need |= (pmax[r] > mrun[r] + 8.f);
    }
    if (__any(need)) {   // rare after first tile: full max-reduce + rescale
        #pragma unroll
        for (int r = 0; r < 4; ++r) {
            float mt = pmax[r];
            mt = fmaxf(mt, __shfl_xor(mt, 1, 16));
            mt = fmaxf(mt, __shfl_xor(mt, 2, 16));
            mt = fmaxf(mt, __shfl_xor(mt, 4, 16));
            mt = fmaxf(mt, __shfl_xor(mt, 8, 16));
            const float mnew = fmaxf(mrun[r], mt);
            const float alpha = fexp2(mrun[r] - mnew);  // first tile: 0
            mrun[r] = mnew;
            lpart[r] *= alpha;
            #pragma unroll
            for (int nf = 0; nf < 4; ++nf) oacc[nf][r] *= alpha;
        }
    }
    #pragma unroll
    for (int r = 0; r < 4; ++r) {
        const float p0 = fexp2(sacc[0][r] - mrun[r]);
        const float p1 = fexp2(sacc[1][r] - mrun[r]);
        const float p2 = fexp2(sacc[2][r] - mrun[r]);
        const float p3 = fexp2(sacc[3][r] - mrun[r]);
        lpart[r] += (p0 + p1) + (p2 + p3);
        uint2 u;
        u.x = cvtpk(p0, p1);     // cols 4*lrow, 4*lrow+1  (nf=0,1)
        u.y = cvtpk(p2, p3);     // cols 4*lrow+2, +3      (nf=2,3)
        *(uint2*)&Ps[rowbase + g * 4 + r][4 * lrow] = u;
    }
}

__global__ __launch_bounds__(512, 4)
void mfma_attn(unsigned short* __restrict__ qkv)
{
    __shared__ unsigned short Ks[2][64][72];   // K tile [buf][kv][dk]
    __shared__ unsigned short Vt[2][64][72];   // V' transposed [buf][dk][c(kv)]
    __shared__ unsigned short Ps[256][76];     // P' [qrow][c(kv)]

    const int tid  = threadIdx.x;
    const int lane = tid & 63;
    const int w    = tid >> 6;
    const int lrow = lane & 15;
    const int g    = lane >> 4;
    const int lk   = g << 3;

    // XCD swizzle: 512 blocks = 8 xcd x (8 bh-groups x 8 q-tiles)
    const int bid  = blockIdx.x;
    const int idx  = bid >> 3;
    const int bh   = (bid & 7) * 8 + (idx & 7);
    const int b  = bh >> 3, h = bh & 7;
    const int s0 = (idx >> 3) << 8;              // q-tile start (256 rows)

    unsigned short* qptr = qkv + ((size_t)(b * SEQ + s0)) * QKVLD + h * DKH;
    const unsigned short* kbase = qkv + ((size_t)(b * SEQ)) * QKVLD + 512 + h * DKH;
    const unsigned short* vbase = qkv + ((size_t)(b * SEQ)) * QKVLD + 1024 + h * DKH;

    // Q fragments for both 16-row sub-tiles (pre-scaled 0.125*log2e via pack)
    bf16x8 qf[2][2];
    #pragma unroll
    for (int sub = 0; sub < 2; ++sub) {
        const unsigned short* qp = qptr + (size_t)(w * 32 + sub * 16 + lrow) * QKVLD;
        qf[sub][0] = *(const bf16x8*)(qp + lk);
        qf[sub][1] = *(const bf16x8*)(qp + 32 + lk);
    }

    // staging indices
    const int kr = tid >> 3, kc = (tid & 7) << 3;   // K: 64 rows x 64 cols
    const int vr = tid & 63, vc = (tid >> 6) << 3;  // V: row=vr, 8-col slab
    const int cvr = ((vr & 15) << 2) | (vr >> 4);   // permuted col of kv=vr

    uint4 kreg, vreg;
    auto loadKV = [&](int t0) {
        kreg = *(const uint4*)(kbase + (size_t)(t0 + kr) * QKVLD + kc);
        vreg = *(const uint4*)(vbase + (size_t)(t0 + vr) * QKVLD + vc);
    };
    loadKV(0);

    const f32x4 zero = {0.f, 0.f, 0.f, 0.f};
    f32x4 oacc0[4], oacc1[4];
    float m0[4], l0[4], m1[4], l1[4];
    #pragma unroll
    for (int i = 0; i < 4; ++i) {
        oacc0[i] = zero; oacc1[i] = zero;
        m0[i] = -INFINITY; m1[i] = -INFINITY; l0[i] = 0.f; l1[i] = 0.f;
    }

    for (int t0 = 0; t0 < SEQ; t0 += 64) {
        const int cur = (t0 >> 6) & 1;
        // write staged K/V regs into buf[cur]; single barrier per tile
        // (r11-proven double-buffer discipline).
        *(uint4*)&Ks[cur][kr][kc] = kreg;
        {
            const unsigned short* vu = (const unsigned short*)&vreg;
            #pragma unroll
            for (int j = 0; j < 8; ++j) Vt[cur][vc + j][cvr] = vu[j];
        }
        __syncthreads();

        if (t0 + 64 < SEQ) loadKV(t0 + 64);   // prefetch, in flight over compute

        // S = Q K^T for both sub-tiles; kf shared (read once, 2 MFMAs)
        f32x4 s0a[4], s1a[4];
        #pragma unroll
        for (int nf = 0; nf < 4; ++nf) { s0a[nf] = zero; s1a[nf] = zero; }
        __builtin_amdgcn_s_setprio(1);
        #pragma unroll
        for (int kk = 0; kk < 2; ++kk) {
            #pragma unroll
            for (int nf = 0; nf < 4; ++nf) {
                const bf16x8 kf = *(const bf16x8*)&Ks[cur][nf * 16 + lrow][kk * 32 + lk];
                s0a[nf] = mfma16(qf[0][kk], kf, s0a[nf]);
                s1a[nf] = mfma16(qf[1][kk], kf, s1a[nf]);
            }
        }
        __builtin_amdgcn_s_setprio(0);

        softmax_store(s0a, m0, l0, oacc0, Ps, w * 32,      g, lrow);
        softmax_store(s1a, m1, l1, oacc1, Ps, w * 32 + 16, g, lrow);

        // O += P' V'   (vf shared across sub-tiles)
        __builtin_amdgcn_s_setprio(1);
        #pragma unroll
        for (int kk = 0; kk < 2; ++kk) {
            const bf16x8 pf0 = *(const bf16x8*)&Ps[w * 32 + lrow][kk * 32 + lk];
            const bf16x8 pf1 = *(const bf16x8*)&Ps[w * 32 + 16 + lrow][kk * 32 + lk];
            #pragma unroll
            for (int nf = 0; nf < 4; ++nf) {
                const bf16x8 vf = *(const bf16x8*)&Vt[cur][nf * 16 + lrow][kk * 32 + lk];
                oacc0[nf] = mfma16(pf0, vf, oacc0[nf]);
                oacc1[nf] = mfma16(pf1, vf, oacc1[nf]);
            }
        }
        __builtin_amdgcn_s_setprio(0);
    }

    // final row-sum reductions, normalize, write O bf16 in place
    #pragma unroll
    for (int r = 0; r < 4; ++r) {
        float l = l0[r];
        l += __shfl_xor(l, 1, 16);
        l += __shfl_xor(l, 2, 16);
        l += __shfl_xor(l, 4, 16);
        l += __shfl_xor(l, 8, 16);
        const float inv = 1.f / l;
        #pragma unroll
        for (int nf = 0; nf < 4; ++nf)
            qptr[(size_t)(w * 32 + g * 4 + r) * QKVLD + nf * 16 + lrow] =
                f2bf(oacc0[nf][r] * inv);
    }
    #pragma unroll
    for (int r = 0; r < 4; ++r) {
        float l = l1[r];
        l += __shfl_xor(l, 1, 16);
        l += __shfl_xor(l, 2, 16);
        l += __shfl_xor(l, 4, 16);
        l += __shfl_xor(l, 8, 16);
        const float inv = 1.f / l;
        #pragma unroll
        for (int nf = 0; nf < 4; ++nf)
            qptr[(size_t)(w * 32 + 16 + g * 4 + r) * QKVLD + nf * 16 + lrow] =
                f2bf(oacc1[nf][r] * inv);
    }
}

// ---------------------------------------------------------------------------
// LayerNorm rows of 512; one wave per row. WF32: fp32 out; WB16: bf16 out.
// ---------------------------------------------------------------------------
template<bool WF32, bool WB16>
__global__ __launch_bounds__(256)
void ln_kernel(const float* __restrict__ in, const float* __restrict__ gg,
               const float* __restrict__ bb, float* __restrict__ outf,
               unsigned short* __restrict__ outb)
{
    const int row = blockIdx.x * 4 + (threadIdx.x >> 6);
    const int lane = threadIdx.x & 63;
    const float* p = in + (size_t)row * D_MODEL;

    const float4 a = *(const float4*)(p + lane * 4);
    const float4 c = *(const float4*)(p + 256 + lane * 4);
    float sum = a.x + a.y + a.z + a.w + c.x + c.y + c.z + c.w;
    float sq  = a.x*a.x + a.y*a.y + a.z*a.z + a.w*a.w
              + c.x*c.x + c.y*c.y + c.z*c.z + c.w*c.w;
    #pragma unroll
    for (int msk = 1; msk < 64; msk <<= 1) {
        sum += __shfl_xor(sum, msk, 64);
        sq  += __shfl_xor(sq,  msk, 64);
    }
    const float mean = sum * (1.f / 512.f);
    const float var  = sq * (1.f / 512.f) - mean * mean;
    const float rs   = rsqrtf(var + 1e-5f);

    const float4 g0 = *(const float4*)(gg + lane * 4);
    const float4 g1 = *(const float4*)(gg + 256 + lane * 4);
    const float4 b0 = *(const float4*)(bb + lane * 4);
    const float4 b1 = *(const float4*)(bb + 256 + lane * 4);

    float4 o0, o1;
    o0.x = (a.x - mean) * rs * g0.x + b0.x;
    o0.y = (a.y - mean) * rs * g0.y + b0.y;
    o0.z = (a.z - mean) * rs * g0.z + b0.z;
    o0.w = (a.w - mean) * rs * g0.w + b0.w;
    o1.x = (c.x - mean) * rs * g1.x + b1.x;
    o1.y = (c.y - mean) * rs * g1.y + b1.y;
    o1.z = (c.z - mean) * rs * g1.z + b1.z;
    o1.w = (c.w - mean) * rs * g1.w + b1.w;
    if constexpr (WF32) {
        *(float4*)(outf + (size_t)row * D_MODEL + lane * 4) = o0;
        *(float4*)(outf + (size_t)row * D_MODEL + 256 + lane * 4) = o1;
    }
    if constexpr (WB16) {
        uint2 pa, pb;
        pa.x = cvtpk(o0.x, o0.y);
        pa.y = cvtpk(o0.z, o0.w);
        pb.x = cvtpk(o1.x, o1.y);
        pb.y = cvtpk(o1.z, o1.w);
        *(uint2*)(outb + (size_t)row * D_MODEL + lane * 4) = pa;
        *(uint2*)(outb + (size_t)row * D_MODEL + 256 + lane * 4) = pb;
    }
}

// ---------------------------------------------------------------------------
// fp32 -> bf16 cast, 8 elems/thread
// ---------------------------------------------------------------------------
__global__ __launch_bounds__(256)
void cast_bf16(const float* __restrict__ in, unsigned short* __restrict__ out)
{
    const size_t i = ((size_t)blockIdx.x * 256 + threadIdx.x) * 8;
    const float4 a = *(const float4*)(in + i);
    const float4 b = *(const float4*)(in + i + 4);
    uint4 o;
    o.x = cvtpk(a.x, a.y);
    o.y = cvtpk(a.z, a.w);
    o.z = cvtpk(b.x, b.y);
    o.w = cvtpk(b.z, b.w);
    *(uint4*)(out + i) = o;
}

// ---------------------------------------------------------------------------
// Weight packing: per-head q/k/v weights -> rows 0..511 / 512..1023 /
// 1024..1535 of Wqkv[1536][512] bf16. q scaled by 0.125*log2e (exp2 softmax).
// ---------------------------------------------------------------------------
__global__ __launch_bounds__(256)
void pack_qkv(const float* __restrict__ wq, const float* __restrict__ wk,
              const float* __restrict__ wv, unsigned short* __restrict__ Wqkv)
{
    const int idx = blockIdx.x * 256 + threadIdx.x;   // n*512 + d, n in 0..511
    const int n = idx >> 9, d = idx & 511;
    const int h = n >> 6, c = n & 63;
    const size_t src = ((size_t)h * 512 + d) * 64 + c;
    Wqkv[idx]                 = f2bf(wq[src] * 0.18033688f);  // 0.125 * log2(e)
    Wqkv[idx + 512 * 512]     = f2bf(wk[src]);
    Wqkv[idx + 2 * 512 * 512] = f2bf(wv[src]);
}

// LDS-tiled transpose-cast: in fp32 [K][N] -> out bf16 [N][K], 32x32 tiles,
// coalesced reads and writes.
__global__ __launch_bounds__(256)
void pack_t(const float* __restrict__ in, unsigned short* __restrict__ out,
            int K, int N)
{
    __shared__ float t[32][33];
    const int kb = blockIdx.x << 5, nb = blockIdx.y << 5;
    const int c = threadIdx.x & 31, r0 = threadIdx.x >> 5;   // 8 row-groups
    #pragma unroll
    for (int j = 0; j < 32; j += 8)
        t[r0 + j][c] = in[(size_t)(kb + r0 + j) * N + nb + c];
    __syncthreads();
    #pragma unroll
    for (int j = 0; j < 32; j += 8)
        out[(size_t)(nb + r0 + j) * K + kb + c] = f2bf(t[c][r0 + j]);
}

// ---------------------------------------------------------------------------
extern "C" void kernel_launch(void* const* d_in, const int* in_sizes, int n_in,
                              void* d_out, int out_size, void* d_ws, size_t ws_size,
                              hipStream_t stream)
{
    (void)in_sizes; (void)n_in; (void)out_size;

    const float* x    = (const float*)d_in[0];
    const float* wq   = (const float*)d_in[1];
    const float* wk   = (const float*)d_in[2];
    const float* wv   = (const float*)d_in[3];
    const float* wo   = (const float*)d_in[4];
    const float* w1   = (const float*)d_in[5];
    const float* b1   = (const float*)d_in[6];
    const float* w2   = (const float*)d_in[7];
    const float* b2   = (const float*)d_in[8];
    const float* ln1g = (const float*)d_in[9];
    const float* ln1b = (const float*)d_in[10];
    const float* ln2g = (const float*)d_in[11];
    const float* ln2b = (const float*)d_in[12];
    float* out = (float*)d_out;

    // ---- workspace layout (bytes), fixed part ~90.2 MB ----
    const size_t QKV_BYTES = (size_t)MROWS * QKVLD * 2;      // 50.33 MB
    const size_t Y_BYTES   = (size_t)MROWS * D_MODEL * 4;    // 33.55 MB
    unsigned char* base = (unsigned char*)d_ws;
    unsigned short* qkv  = (unsigned short*)(base);
    float*          y    = (float*)(base + QKV_BYTES);
    unsigned short* Wqkv = (unsigned short*)(base + QKV_BYTES + Y_BYTES);
    unsigned short* wo_t = Wqkv + 3 * 512 * 512;
    unsigned short* w1_t = wo_t + 512 * 512;
    unsigned short* w2_t = w1_t + 2048 * 512;
    unsigned short* hid  = w2_t + 2048 * 512;

    const size_t hid_off = (size_t)((unsigned char*)hid - base);
    const size_t avail = (ws_size > hid_off) ? (ws_size - hid_off) : 0;
    int chunk = (int)(avail / ((size_t)DFF * 2));
    chunk &= ~127;
    if (chunk > MROWS) chunk = MROWS;
    if (chunk < 128)   chunk = 128;

    float* y2 = (float*)qkv;                       // qkv dead after WO GEMM
    // d_out doubles as scratch: xb (bf16 x) until LN1, then x1b (bf16 x1).
    unsigned short* xb  = (unsigned short*)d_out;
    unsigned short* x1b = (unsigned short*)d_out;

    // ---- weight packing + x cast ----
    pack_qkv<<<1024, 256, 0, stream>>>(wq, wk, wv, Wqkv);
    pack_t<<<dim3(16, 16), 256, 0, stream>>>(wo, wo_t, 512, 512);
    pack_t<<<dim3(16, 64), 256, 0, stream>>>(w1, w1_t, 512, 2048);
    pack_t<<<dim3(64, 16), 256, 0, stream>>>(w2, w2_t, 2048, 512);
    cast_bf16<<<(MROWS * D_MODEL) / (256 * 8), 256, 0, stream>>>(x, xb);

    const dim3 blk(256);

    // 1) fused q|k|v projection: xb[M][512] @ Wqkv^T -> qkv[M][1536]
    mfma_gemm<false, false, 0, false>
        <<<dim3(12, MROWS / 128), blk, 0, stream>>>(xb, Wqkv, nullptr, nullptr,
                                                    qkv, 512, 512, QKVLD);

    // 2) flash attention (O bf16 in place over q section), XCD-swizzled grid
    mfma_attn<<<dim3(512), dim3(512), 0, stream>>>(qkv);

    // 3) y = O @ wo + x   (fp32 out, fp32 residual)
    mfma_gemm<false, false, 1, true>
        <<<dim3(4, MROWS / 128), blk, 0, stream>>>(qkv, wo_t, nullptr, x, y,
                                                   512, QKVLD, 512);

    // 4) x1 = LN1(y): bf16 only into d_out (FFN2 residual reads bf16)
    ln_kernel<false, true><<<MROWS / 4, blk, 0, stream>>>(y, ln1g, ln1b,
                                                          nullptr, x1b);

    // 5+6) FFN, chunked over rows (chunk multiple of 128)
    for (int r0 = 0; r0 < MROWS; r0 += chunk) {
        const int rows = (r0 + chunk <= MROWS) ? chunk : (MROWS - r0);
        mfma_gemm<true, true, 0, false>
            <<<dim3(DFF / 128, rows / 128), blk, 0, stream>>>(
                x1b + (size_t)r0 * D_MODEL, w1_t, b1, nullptr, hid,
                512, 512, DFF);
        mfma_gemm<true, false, 2, true>
            <<<dim3(4, rows / 128), blk, 0, stream>>>(
                hid, w2_t, b2, x1b + (size_t)r0 * D_MODEL,
                y2 + (size_t)r0 * D_MODEL, DFF, DFF, 512);
    }

    // 7) out = LN2(y2)
    ln_kernel<true, false><<<MROWS / 4, blk, 0, stream>>>(y2, ln2g, ln2b,
                                                          out, nullptr);
}

// Round 13
// 292.169 us; speedup vs baseline: 1.0285x; 1.0092x over previous
//
#include <hip/hip_runtime.h>
#include <hip/hip_bf16.h>
#include <math.h>

// ---------------------------------------------------------------------------
// EncoderLayer, bf16-MFMA mixed precision for MI355X (gfx950).
// B=8, S=2048, D=512, H=8, DK=64, DFF=2048, M=16384.
// Round-13: attention rewritten around SWAPPED QK^T with 32x32x16 MFMA
// (T12): mfma(A=K, B=Q) puts q in D-columns -> each lane owns one q-row,
// softmax is in-lane (defer-max, no shuffle trees), P converts to PV's
// A-operand via cvt_pk + v_permlane32_swap (m214 recipe) -- the P LDS
// round-trip is deleted (LDS 75.8 -> 36.9 KB). V staged as plain [dk][kv]
// transpose. GEMM/LN/pack byte-identical to round 12.
// ---------------------------------------------------------------------------

#define D_MODEL 512
#define NHEAD   8
#define DKH     64
#define SEQ     2048
#define BATCH   8
#define DFF     2048
#define MROWS   (BATCH * SEQ)          // 16384
#define QKVLD   1536                   // fused q|k|v row stride

typedef __bf16 bf16x8 __attribute__((ext_vector_type(8)));
typedef float  f32x4  __attribute__((ext_vector_type(4)));
typedef float  f32x16 __attribute__((ext_vector_type(16)));

__device__ __forceinline__ unsigned short f2bf(float f) {
    union { float f; unsigned u; } v; v.f = f;
    return (unsigned short)((v.u + 0x7FFFu + ((v.u >> 16) & 1u)) >> 16);
}

__device__ __forceinline__ float bf2f(unsigned short u) {
    union { unsigned u; float f; } v; v.u = (unsigned)u << 16;
    return v.f;
}

__device__ __forceinline__ unsigned cvtpk(float a, float b) {   // bf16(a)|bf16(b)<<16
    unsigned r;
    asm("v_cvt_pk_bf16_f32 %0, %1, %2" : "=v"(r) : "v"(a), "v"(b));
    return r;
}

__device__ __forceinline__ float fexp2(float x) {   // raw v_exp_f32 (2^x)
    float r; asm("v_exp_f32 %0, %1" : "=v"(r) : "v"(x)); return r;
}

// v_permlane32_swap_b32: x<-[x(0:31)|y(0:31)], y<-[x(32:63)|y(32:63)]
__device__ __forceinline__ void plswap(unsigned& x, unsigned& y) {
    asm volatile("v_permlane32_swap_b32 %0, %1" : "+v"(x), "+v"(y));
}

__device__ __forceinline__ unsigned fbits(float f) {
    union { float f; unsigned u; } v; v.f = f; return v.u;
}
__device__ __forceinline__ float bitsf(unsigned u) {
    union { unsigned u; float f; } v; v.u = u; return v.f;
}

__device__ __forceinline__ f32x4 mfma16(bf16x8 a, bf16x8 b, f32x4 c) {
    return __builtin_amdgcn_mfma_f32_16x16x32_bf16(a, b, c, 0, 0, 0);
}
__device__ __forceinline__ f32x16 mfma32(bf16x8 a, bf16x8 b, f32x16 c) {
    return __builtin_amdgcn_mfma_f32_32x32x16_bf16(a, b, c, 0, 0, 0);
}

// async global -> LDS, 16 B per lane; lds base must be wave-uniform
__device__ __forceinline__ void gld_lds16(const unsigned short* g, unsigned short* l) {
    __builtin_amdgcn_global_load_lds(
        (const __attribute__((address_space(1))) unsigned int*)g,
        (__attribute__((address_space(3))) unsigned int*)l, 16, 0, 0);
}

// ---------------------------------------------------------------------------
// bf16 MFMA GEMM (unchanged from round 12): 128x128 tile, BK=32, 4 waves,
// double-buffered global_load_lds staging. RESMODE: 0 none, 1 fp32, 2 bf16.
// ---------------------------------------------------------------------------
template<bool BIAS, bool RELU, int RESMODE, bool OUTF32>
__global__ __launch_bounds__(256)
void mfma_gemm(const unsigned short* __restrict__ Av,
               const unsigned short* __restrict__ Bt,
               const float* __restrict__ bias, const void* __restrict__ resv,
               void* __restrict__ Cv, int Kdim, int lda, int ldc)
{
    __shared__ unsigned short As[2][128][32];
    __shared__ unsigned short Bs[2][128][32];

    const int tid  = threadIdx.x;
    const int lane = tid & 63;
    const int w    = tid >> 6;
    const int mq   = (w >> 1) << 6;
    const int nq   = (w & 1) << 6;
    const int lrow = lane & 15;
    const int g    = lane >> 4;
    const int lk   = g << 3;

    const int row0 = blockIdx.y << 7;
    const int col0 = blockIdx.x << 7;

    const int c0   = w << 5;
    const int srow = lane >> 2;
    const int scol = (lane & 3) << 3;
    const size_t aoff = (size_t)(row0 + c0 + srow) * lda  + scol;
    const size_t boff = (size_t)(col0 + c0 + srow) * Kdim + scol;

    auto stage = [&](int buf, int kt) {
        gld_lds16(Av + aoff + kt,                        &As[buf][c0     ][0]);
        gld_lds16(Av + aoff + (size_t)16 * lda  + kt,    &As[buf][c0 + 16][0]);
        gld_lds16(Bt + boff + kt,                        &Bs[buf][c0     ][0]);
        gld_lds16(Bt + boff + (size_t)16 * Kdim + kt,    &Bs[buf][c0 + 16][0]);
    };

    const f32x4 zero = {0.f, 0.f, 0.f, 0.f};
    f32x4 acc[4][4];
    #pragma unroll
    for (int i = 0; i < 4; ++i)
        #pragma unroll
        for (int j = 0; j < 4; ++j) acc[i][j] = zero;

    stage(0, 0);
    __syncthreads();

    int cur = 0;
    for (int kt = 0; kt < Kdim; kt += 32) {
        if (kt + 32 < Kdim) stage(cur ^ 1, kt + 32);

        bf16x8 af[4], bfv[4];
        #pragma unroll
        for (int mf = 0; mf < 4; ++mf)
            af[mf] = *(const bf16x8*)&As[cur][mq + mf * 16 + lrow][lk];
        #pragma unroll
        for (int nf = 0; nf < 4; ++nf)
            bfv[nf] = *(const bf16x8*)&Bs[cur][nq + nf * 16 + lrow][lk];
        #pragma unroll
        for (int mf = 0; mf < 4; ++mf)
            #pragma unroll
            for (int nf = 0; nf < 4; ++nf)
                acc[mf][nf] = mfma16(af[mf], bfv[nf], acc[mf][nf]);

        __syncthreads();
        cur ^= 1;
    }

    const int orow = row0 + mq + g * 4;
    const int ocol = col0 + nq + lrow;
    #pragma unroll
    for (int mf = 0; mf < 4; ++mf) {
        #pragma unroll
        for (int nf = 0; nf < 4; ++nf) {
            const int cc = ocol + nf * 16;
            float bv = 0.f;
            if constexpr (BIAS) bv = bias[cc];
            float v[4];
            #pragma unroll
            for (int r = 0; r < 4; ++r) {
                const int rr = orow + mf * 16 + r;
                v[r] = acc[mf][nf][r];
                if constexpr (BIAS) v[r] += bv;
                if constexpr (RELU) v[r] = fmaxf(v[r], 0.f);
                if constexpr (RESMODE == 1)
                    v[r] += ((const float*)resv)[(size_t)rr * ldc + cc];
                if constexpr (RESMODE == 2)
                    v[r] += bf2f(((const unsigned short*)resv)[(size_t)rr * ldc + cc]);
                if constexpr (OUTF32) ((float*)Cv)[(size_t)rr * ldc + cc] = v[r];
            }
            if constexpr (!OUTF32) {
                const unsigned u01 = cvtpk(v[0], v[1]);
                const unsigned u23 = cvtpk(v[2], v[3]);
                unsigned short* cp = (unsigned short*)Cv + (size_t)(orow + mf * 16) * ldc + cc;
                cp[0]                 = (unsigned short)u01;
                cp[(size_t)ldc]       = (unsigned short)(u01 >> 16);
                cp[(size_t)ldc * 2]   = (unsigned short)u23;
                cp[(size_t)ldc * 3]   = (unsigned short)(u23 >> 16);
            }
        }
    }
}

// ---------------------------------------------------------------------------
// Flash attention v6 (swapped QK^T, 32x32x16 MFMA, in-register P):
// 8 waves x 32 q-rows = 256 q-rows/block, 512 blocks, KV tiles of 64
// double-buffered (single barrier/tile, r12 discipline).
// QK: D[kv][q] = mfma(A=K, B=Q): lane owns q = lane&31 (h = lane>>5 selects
// the kv half); reg r holds kv = (r&3)+8*(r>>2)+4h (per 32-kv block).
// Softmax in-lane with defer-max (pair-max via permlane32_swap).
// P -> PV A-frags: A0=cvtpk(p0,p1),A1=cvtpk(p2,p3),B0=cvtpk(p4,p5),
// B1=cvtpk(p6,p7); plswap(A0,B0); plswap(A1,B1); frag={A0,A1,B0,B1}.
// PV: O[q][dk] = mfma(A=P, B=V), V in LDS as plain transpose [dk][kv].
// ---------------------------------------------------------------------------
__global__ __launch_bounds__(512, 4)
void mfma_attn(unsigned short* __restrict__ qkv)
{
    __shared__ unsigned short Ks[2][64][72];   // K tile [buf][kv][dk]
    __shared__ unsigned short Vt[2][64][72];   // V transposed [buf][dk][kv]

    const int tid  = threadIdx.x;
    const int lane = tid & 63;
    const int w    = tid >> 6;
    const int q32  = lane & 31;      // this lane's q (and kv-row selector)
    const int h    = lane >> 5;      // kv half / k-chunk selector

    // XCD swizzle: 512 blocks = 8 xcd x (8 bh-groups x 8 q-tiles)
    const int bid  = blockIdx.x;
    const int idx  = bid >> 3;
    const int bh   = (bid & 7) * 8 + (idx & 7);
    const int b  = bh >> 3, hd = bh & 7;
    const int s0 = (idx >> 3) << 8;              // q-tile start (256 rows)

    unsigned short* qptr = qkv + ((size_t)(b * SEQ + s0)) * QKVLD + hd * DKH;
    const unsigned short* kbase = qkv + ((size_t)(b * SEQ)) * QKVLD + 512 + hd * DKH;
    const unsigned short* vbase = qkv + ((size_t)(b * SEQ)) * QKVLD + 1024 + hd * DKH;

    // Q fragments (B-operand): lane -> Q[w*32+q32][dk = 16t + 8h .. +7]
    bf16x8 qf[4];
    {
        const unsigned short* qp = qptr + (size_t)(w * 32 + q32) * QKVLD + 8 * h;
        #pragma unroll
        for (int t = 0; t < 4; ++t)
            qf[t] = *(const bf16x8*)(qp + 16 * t);
    }

    // staging indices (as r12; V now plain transpose, no permute)
    const int kr = tid >> 3, kc = (tid & 7) << 3;
    const int vr = tid & 63, vc = (tid >> 6) << 3;

    uint4 kreg, vreg;
    auto loadKV = [&](int t0) {
        kreg = *(const uint4*)(kbase + (size_t)(t0 + kr) * QKVLD + kc);
        vreg = *(const uint4*)(vbase + (size_t)(t0 + vr) * QKVLD + vc);
    };
    loadKV(0);

    f32x16 oacc0, oacc1;             // O[q rows][dk = dt*32 + q32]
    #pragma unroll
    for (int i = 0; i < 16; ++i) { oacc0[i] = 0.f; oacc1[i] = 0.f; }
    float m = -INFINITY, lsum = 0.f;

    for (int t0 = 0; t0 < SEQ; t0 += 64) {
        const int cur = (t0 >> 6) & 1;
        *(uint4*)&Ks[cur][kr][kc] = kreg;
        {
            const unsigned short* vu = (const unsigned short*)&vreg;
            #pragma unroll
            for (int j = 0; j < 8; ++j) Vt[cur][vc + j][vr] = vu[j];
        }
        __syncthreads();

        if (t0 + 64 < SEQ) loadKV(t0 + 64);   // prefetch over compute

        // ---- QK^T swapped: s[blk] = K_blk x Q  -> D[kv][q] ----
        f32x16 sa0, sa1;
        #pragma unroll
        for (int i = 0; i < 16; ++i) { sa0[i] = 0.f; sa1[i] = 0.f; }
        __builtin_amdgcn_s_setprio(1);
        #pragma unroll
        for (int t = 0; t < 4; ++t) {
            const bf16x8 k0 = *(const bf16x8*)&Ks[cur][q32     ][16 * t + 8 * h];
            const bf16x8 k1 = *(const bf16x8*)&Ks[cur][32 + q32][16 * t + 8 * h];
            sa0 = mfma32(k0, qf[t], sa0);
            sa1 = mfma32(k1, qf[t], sa1);
        }
        __builtin_amdgcn_s_setprio(0);

        // ---- in-lane softmax (exp2 domain, defer-max) ----
        float pmax = fmaxf(sa0[0], sa1[0]);
        #pragma unroll
        for (int r = 1; r < 16; ++r)
            pmax = fmaxf(pmax, fmaxf(sa0[r], sa1[r]));
        // pair-max across the kv halves (lane <-> lane^32)
        {
            unsigned x = fbits(pmax), y = x;
            plswap(x, y);
            const float partner = (lane < 32) ? bitsf(y) : bitsf(x);
            pmax = fmaxf(pmax, partner);      // symmetric across the pair
        }
        if (__any(pmax > m + 8.f)) {          // rare after first tile
            const float mnew = fmaxf(m, pmax);
            const float alpha = fexp2(m - mnew);   // first tile: 2^-inf = 0
            m = mnew;
            lsum *= alpha;
            #pragma unroll
            for (int r = 0; r < 16; ++r) {
                const int qr = (r & 3) + 8 * (r >> 2) + 4 * h;
                const float ar = __shfl(alpha, qr, 64);
                oacc0[r] *= ar;
                oacc1[r] *= ar;
            }
        }
        // exp2 in place + lazy per-lane sum
        #pragma unroll
        for (int r = 0; r < 16; ++r) {
            sa0[r] = fexp2(sa0[r] - m);
            sa1[r] = fexp2(sa1[r] - m);
            lsum += sa0[r] + sa1[r];
        }

        // ---- pack P to PV A-frags (cvt_pk + permlane32_swap) ----
        bf16x8 pa[4];
        #pragma unroll
        for (int blk = 0; blk < 2; ++blk) {
            const f32x16& p = blk ? sa1 : sa0;
            #pragma unroll
            for (int tt = 0; tt < 2; ++tt) {
                unsigned a0 = cvtpk(p[8 * tt + 0], p[8 * tt + 1]);
                unsigned a1 = cvtpk(p[8 * tt + 2], p[8 * tt + 3]);
                unsigned b0 = cvtpk(p[8 * tt + 4], p[8 * tt + 5]);
                unsigned b1 = cvtpk(p[8 * tt + 6], p[8 * tt + 7]);
                plswap(a0, b0);
                plswap(a1, b1);
                union { uint4 u; bf16x8 v; } cvt;
                cvt.u.x = a0; cvt.u.y = a1; cvt.u.z = b0; cvt.u.w = b1;
                pa[blk * 2 + tt] = cvt.v;
            }
        }

        // ---- O += P V  (B = V from plain-transposed LDS) ----
        __builtin_amdgcn_s_setprio(1);
        #pragma unroll
        for (int ttg = 0; ttg < 4; ++ttg) {    // kv 16-chunks
            const bf16x8 vf0 = *(const bf16x8*)&Vt[cur][q32     ][16 * ttg + 8 * h];
            const bf16x8 vf1 = *(const bf16x8*)&Vt[cur][32 + q32][16 * ttg + 8 * h];
            oacc0 = mfma32(pa[ttg], vf0, oacc0);
            oacc1 = mfma32(pa[ttg], vf1, oacc1);
        }
        __builtin_amdgcn_s_setprio(0);
    }

    // ---- final: pair-combine row sums, normalize, write O in place ----
    float ltot;
    {
        unsigned x = fbits(lsum), y = x;
        plswap(x, y);
        const float partner = (lane < 32) ? bitsf(y) : bitsf(x);
        ltot = lsum + partner;                // symmetric: full row sum for q
    }
    const float inv = 1.f / ltot;
    #pragma unroll
    for (int r = 0; r < 16; ++r) {
        const int qr = (r & 3) + 8 * (r >> 2) + 4 * h;
        const float invr = __shfl(inv, qr, 64);
        unsigned short* op = qptr + (size_t)(w * 32 + qr) * QKVLD + q32;
        op[0]  = f2bf(oacc0[r] * invr);
        op[32] = f2bf(oacc1[r] * invr);
    }
}

// ---------------------------------------------------------------------------
// LayerNorm rows of 512; one wave per row. WF32: fp32 out; WB16: bf16 out.
// ---------------------------------------------------------------------------
template<bool WF32, bool WB16>
__global__ __launch_bounds__(256)
void ln_kernel(const float* __restrict__ in, const float* __restrict__ gg,
               const float* __restrict__ bb, float* __restrict__ outf,
               unsigned short* __restrict__ outb)
{
    const int row = blockIdx.x * 4 + (threadIdx.x >> 6);
    const int lane = threadIdx.x & 63;
    const float* p = in + (size_t)row * D_MODEL;

    const float4 a = *(const float4*)(p + lane * 4);
    const float4 c = *(const float4*)(p + 256 + lane * 4);
    float sum = a.x + a.y + a.z + a.w + c.x + c.y + c.z + c.w;
    float sq  = a.x*a.x + a.y*a.y + a.z*a.z + a.w*a.w
              + c.x*c.x + c.y*c.y + c.z*c.z + c.w*c.w;
    #pragma unroll
    for (int msk = 1; msk < 64; msk <<= 1) {
        sum += __shfl_xor(sum, msk, 64);
        sq  += __shfl_xor(sq,  msk, 64);
    }
    const float mean = sum * (1.f / 512.f);
    const float var  = sq * (1.f / 512.f) - mean * mean;
    const float rs   = rsqrtf(var + 1e-5f);

    const float4 g0 = *(const float4*)(gg + lane * 4);
    const float4 g1 = *(const float4*)(gg + 256 + lane * 4);
    const float4 b0 = *(const float4*)(bb + lane * 4);
    const float4 b1 = *(const float4*)(bb + 256 + lane * 4);

    float4 o0, o1;
    o0.x = (a.x - mean) * rs * g0.x + b0.x;
    o0.y = (a.y - mean) * rs * g0.y + b0.y;
    o0.z = (a.z - mean) * rs * g0.z + b0.z;
    o0.w = (a.w - mean) * rs * g0.w + b0.w;
    o1.x = (c.x - mean) * rs * g1.x + b1.x;
    o1.y = (c.y - mean) * rs * g1.y + b1.y;
    o1.z = (c.z - mean) * rs * g1.z + b1.z;
    o1.w = (c.w - mean) * rs * g1.w + b1.w;
    if constexpr (WF32) {
        *(float4*)(outf + (size_t)row * D_MODEL + lane * 4) = o0;
        *(float4*)(outf + (size_t)row * D_MODEL + 256 + lane * 4) = o1;
    }
    if constexpr (WB16) {
        uint2 pa, pb;
        pa.x = cvtpk(o0.x, o0.y);
        pa.y = cvtpk(o0.z, o0.w);
        pb.x = cvtpk(o1.x, o1.y);
        pb.y = cvtpk(o1.z, o1.w);
        *(uint2*)(outb + (size_t)row * D_MODEL + lane * 4) = pa;
        *(uint2*)(outb + (size_t)row * D_MODEL + 256 + lane * 4) = pb;
    }
}

// ---------------------------------------------------------------------------
// fp32 -> bf16 cast, 8 elems/thread
// ---------------------------------------------------------------------------
__global__ __launch_bounds__(256)
void cast_bf16(const float* __restrict__ in, unsigned short* __restrict__ out)
{
    const size_t i = ((size_t)blockIdx.x * 256 + threadIdx.x) * 8;
    const float4 a = *(const float4*)(in + i);
    const float4 b = *(const float4*)(in + i + 4);
    uint4 o;
    o.x = cvtpk(a.x, a.y);
    o.y = cvtpk(a.z, a.w);
    o.z = cvtpk(b.x, b.y);
    o.w = cvtpk(b.z, b.w);
    *(uint4*)(out + i) = o;
}

// ---------------------------------------------------------------------------
// Weight packing: per-head q/k/v weights -> rows 0..511 / 512..1023 /
// 1024..1535 of Wqkv[1536][512] bf16. q scaled by 0.125*log2e (exp2 softmax).
// ---------------------------------------------------------------------------
__global__ __launch_bounds__(256)
void pack_qkv(const float* __restrict__ wq, const float* __restrict__ wk,
              const float* __restrict__ wv, unsigned short* __restrict__ Wqkv)
{
    const int idx = blockIdx.x * 256 + threadIdx.x;   // n*512 + d, n in 0..511
    const int n = idx >> 9, d = idx & 511;
    const int h = n >> 6, c = n & 63;
    const size_t src = ((size_t)h * 512 + d) * 64 + c;
    Wqkv[idx]                 = f2bf(wq[src] * 0.18033688f);  // 0.125 * log2(e)
    Wqkv[idx + 512 * 512]     = f2bf(wk[src]);
    Wqkv[idx + 2 * 512 * 512] = f2bf(wv[src]);
}

// LDS-tiled transpose-cast: in fp32 [K][N] -> out bf16 [N][K], 32x32 tiles.
__global__ __launch_bounds__(256)
void pack_t(const float* __restrict__ in, unsigned short* __restrict__ out,
            int K, int N)
{
    __shared__ float t[32][33];
    const int kb = blockIdx.x << 5, nb = blockIdx.y << 5;
    const int c = threadIdx.x & 31, r0 = threadIdx.x >> 5;   // 8 row-groups
    #pragma unroll
    for (int j = 0; j < 32; j += 8)
        t[r0 + j][c] = in[(size_t)(kb + r0 + j) * N + nb + c];
    __syncthreads();
    #pragma unroll
    for (int j = 0; j < 32; j += 8)
        out[(size_t)(nb + r0 + j) * K + kb + c] = f2bf(t[c][r0 + j]);
}

// ---------------------------------------------------------------------------
extern "C" void kernel_launch(void* const* d_in, const int* in_sizes, int n_in,
                              void* d_out, int out_size, void* d_ws, size_t ws_size,
                              hipStream_t stream)
{
    (void)in_sizes; (void)n_in; (void)out_size;

    const float* x    = (const float*)d_in[0];
    const float* wq   = (const float*)d_in[1];
    const float* wk   = (const float*)d_in[2];
    const float* wv   = (const float*)d_in[3];
    const float* wo   = (const float*)d_in[4];
    const float* w1   = (const float*)d_in[5];
    const float* b1   = (const float*)d_in[6];
    const float* w2   = (const float*)d_in[7];
    const float* b2   = (const float*)d_in[8];
    const float* ln1g = (const float*)d_in[9];
    const float* ln1b = (const float*)d_in[10];
    const float* ln2g = (const float*)d_in[11];
    const float* ln2b = (const float*)d_in[12];
    float* out = (float*)d_out;

    // ---- workspace layout (bytes), fixed part ~90.2 MB ----
    const size_t QKV_BYTES = (size_t)MROWS * QKVLD * 2;      // 50.33 MB
    const size_t Y_BYTES   = (size_t)MROWS * D_MODEL * 4;    // 33.55 MB
    unsigned char* base = (unsigned char*)d_ws;
    unsigned short* qkv  = (unsigned short*)(base);
    float*          y    = (float*)(base + QKV_BYTES);
    unsigned short* Wqkv = (unsigned short*)(base + QKV_BYTES + Y_BYTES);
    unsigned short* wo_t = Wqkv + 3 * 512 * 512;
    unsigned short* w1_t = wo_t + 512 * 512;
    unsigned short* w2_t = w1_t + 2048 * 512;
    unsigned short* hid  = w2_t + 2048 * 512;

    const size_t hid_off = (size_t)((unsigned char*)hid - base);
    const size_t avail = (ws_size > hid_off) ? (ws_size - hid_off) : 0;
    int chunk = (int)(avail / ((size_t)DFF * 2));
    chunk &= ~127;
    if (chunk > MROWS) chunk = MROWS;
    if (chunk < 128)   chunk = 128;

    float* y2 = (float*)qkv;                       // qkv dead after WO GEMM
    unsigned short* xb  = (unsigned short*)d_out;  // bf16 x until LN1
    unsigned short* x1b = (unsigned short*)d_out;  // then bf16 x1

    // ---- weight packing + x cast ----
    pack_qkv<<<1024, 256, 0, stream>>>(wq, wk, wv, Wqkv);
    pack_t<<<dim3(16, 16), 256, 0, stream>>>(wo, wo_t, 512, 512);
    pack_t<<<dim3(16, 64), 256, 0, stream>>>(w1, w1_t, 512, 2048);
    pack_t<<<dim3(64, 16), 256, 0, stream>>>(w2, w2_t, 2048, 512);
    cast_bf16<<<(MROWS * D_MODEL) / (256 * 8), 256, 0, stream>>>(x, xb);

    const dim3 blk(256);

    // 1) fused q|k|v projection: xb[M][512] @ Wqkv^T -> qkv[M][1536]
    mfma_gemm<false, false, 0, false>
        <<<dim3(12, MROWS / 128), blk, 0, stream>>>(xb, Wqkv, nullptr, nullptr,
                                                    qkv, 512, 512, QKVLD);

    // 2) flash attention (O bf16 in place over q section), XCD-swizzled grid
    mfma_attn<<<dim3(512), dim3(512), 0, stream>>>(qkv);

    // 3) y = O @ wo + x   (fp32 out, fp32 residual)
    mfma_gemm<false, false, 1, true>
        <<<dim3(4, MROWS / 128), blk, 0, stream>>>(qkv, wo_t, nullptr, x, y,
                                                   512, QKVLD, 512);

    // 4) x1 = LN1(y): bf16 only into d_out (FFN2 residual reads bf16)
    ln_kernel<false, true><<<MROWS / 4, blk, 0, stream>>>(y, ln1g, ln1b,
                                                          nullptr, x1b);

    // 5+6) FFN, chunked over rows (chunk multiple of 128)
    for (int r0 = 0; r0 < MROWS; r0 += chunk) {
        const int rows = (r0 + chunk <= MROWS) ? chunk : (MROWS - r0);
        mfma_gemm<true, true, 0, false>
            <<<dim3(DFF / 128, rows / 128), blk, 0, stream>>>(
                x1b + (size_t)r0 * D_MODEL, w1_t, b1, nullptr, hid,
                512, 512, DFF);
        mfma_gemm<true, false, 2, true>
            <<<dim3(4, rows / 128), blk, 0, stream>>>(
                hid, w2_t, b2, x1b + (size_t)r0 * D_MODEL,
                y2 + (size_t)r0 * D_MODEL, DFF, DFF, 512);
    }

    // 7) out = LN2(y2)
    ln_kernel<true, false><<<MROWS / 4, blk, 0, stream>>>(y2, ln2g, ln2b,
                                                          out, nullptr);
}